// Round 3
// baseline (41337.778 us; speedup 1.0000x reference)
//
#include <hip/hip_runtime.h>
#include <math.h>

#define SZ 300
#define TS 64
#define B_ 512
#define NS 128
#define TT 255
#define G4 256
#define R5 1500
#define RPB 4            // batch rows per block (block-private)
#define NBLK (B_/RPB)    // 128 persistent blocks
#define NTHR 512

__device__ __forceinline__ float sigf(float x){ return 1.f/(1.f+expf(-x)); }

// ---------------------------------------------------------------------------
// Persistent SPINN kernel: each block owns RPB batch rows for all TT steps.
// Rows are fully independent => no inter-block communication ever.
// Per step: P0 schedule update (registers+LDS, thread r), P1 gather h-parts,
// P2 x=[bh|s1h|s2h]@[Wb;Ws1;Ws2], P3 g=x@W_ih+th@W_hh, P4 LSTM pointwise +
// logits/nll, P5 r-GEMM (reduce rows only, predicated), P6 tree pointwise +
// in-place stack write. Stack slots holding shifted tokens are never
// materialized (indirection to tokens); only reduce outputs are written.
// ---------------------------------------------------------------------------
__global__ __launch_bounds__(NTHR) void kSpinn(
    const float* __restrict__ tokens, const float* __restrict__ Wb,
    const float* __restrict__ Ws1, const float* __restrict__ Ws2,
    const float* __restrict__ W_ih, const float* __restrict__ W_hh,
    const float* __restrict__ Wt, const float* __restrict__ bt,
    const float* __restrict__ WL, const float* __restrict__ WR,
    const float* __restrict__ Wtr, const float* __restrict__ bL,
    const int* __restrict__ trans, float* __restrict__ stack,
    float* __restrict__ out, float* __restrict__ nllrow)
{
    __shared__ __align__(16) float sInp[RPB][912];   // [bh|s1h|s2h] @0/304/608
    __shared__ __align__(16) float sX[RPB][G4];
    __shared__ __align__(16) float sG[RPB][G4];
    __shared__ __align__(16) float sTh[RPB][TS];
    __shared__ __align__(16) float sTc[RPB][TS];
    __shared__ __align__(16) float sR[RPB][R5];
    __shared__ int srcS[RPB][NS];                    // slot source: >=0 token idx, -1 materialized
    __shared__ int sTr[RPB], sS1[RPB], sS2[RPB];
    __shared__ int sS1sl[RPB], sS2sl[RPB], sWsl[RPB], sBpl[RPB];
    __shared__ float sNll[RPB];

    const int tid = threadIdx.x;
    const int b0 = blockIdx.x * RPB;

    // ---- init persistent state ----
    for (int i = tid; i < RPB*TS; i += NTHR) { sTh[i>>6][i&63] = 0.f; sTc[i>>6][i&63] = 0.f; }
    if (tid < RPB) sNll[tid] = 0.f;
    int sp = 0, bp = 0, prevTr = 0;    // meaningful only in threads 0..RPB-1

    for (int t = 0; t < TT; ++t) {
        __syncthreads();   // P6 of prev step done before meta update / gather

        // ---- P0: per-row schedule update (thread r owns row r) ----
        if (tid < RPB) {
            int r = tid, b = b0 + r;
            if (t > 0) {
                if (prevTr) { srcS[r][sp-2] = -1; sp -= 1; }
                else        { if (sp < NS) srcS[r][sp] = bp; sp += 1; bp += 1; }
            }
            int tr = trans[b*TT + t];
            sTr[r] = tr; prevTr = tr;
            int s1sl = min(max(sp-1,0), NS-1), s2sl = min(max(sp-2,0), NS-1);
            sS1sl[r] = s1sl; sS2sl[r] = s2sl;
            sS1[r] = (sp >= 1) ? srcS[r][s1sl] : -3;   // -3 => zeros
            sS2[r] = (sp >= 2) ? srcS[r][s2sl] : -3;
            sWsl[r] = min(max(sp-2,0), NS-1);
            sBpl[r] = min(bp, NS-1);
        }
        __syncthreads();

        // ---- P1: gather bh / s1h / s2h into LDS ----
        for (int idx = tid; idx < RPB*912; idx += NTHR) {
            int r = idx / 912, pos = idx - r*912;
            int b = b0 + r;
            float v = 0.f;
            if (pos < 304) {
                int i = pos;
                if (i < SZ) v = tokens[((size_t)b*NS + sBpl[r])*600 + i];
            } else if (pos < 608) {
                int i = pos - 304, c = sS1[r];
                if (i < SZ && c != -3)
                    v = (c >= 0) ? tokens[((size_t)b*NS + c)*600 + i]
                                 : stack [((size_t)b*NS + sS1sl[r])*600 + i];
            } else {
                int i = pos - 608, c = sS2[r];
                if (i < SZ && c != -3)
                    v = (c >= 0) ? tokens[((size_t)b*NS + c)*600 + i]
                                 : stack [((size_t)b*NS + sS2sl[r])*600 + i];
            }
            sInp[r][pos] = v;
        }
        __syncthreads();

        // ---- P2: x = bh@Wb + s1h@Ws1 + s2h@Ws2  (thread = col j, 2 rows) ----
        {
            const int j = tid & 255, h = tid >> 8;
            float a0 = 0.f, a1 = 0.f;
            const float* i0 = sInp[2*h];
            const float* i1 = sInp[2*h+1];
            #pragma unroll 1
            for (int m = 0; m < 3; ++m) {
                const float* W = (m == 0) ? Wb : ((m == 1) ? Ws1 : Ws2);
                const int off = m * 304;
                for (int k = 0; k < SZ; k += 4) {
                    float w0 = W[(k+0)*G4+j], w1 = W[(k+1)*G4+j];
                    float w2 = W[(k+2)*G4+j], w3 = W[(k+3)*G4+j];
                    float4 v0 = *(const float4*)&i0[off+k];
                    float4 v1 = *(const float4*)&i1[off+k];
                    a0 += v0.x*w0 + v0.y*w1 + v0.z*w2 + v0.w*w3;
                    a1 += v1.x*w0 + v1.y*w1 + v1.z*w2 + v1.w*w3;
                }
            }
            sX[2*h][j] = a0; sX[2*h+1][j] = a1;
        }
        __syncthreads();

        // ---- P3: g = x@W_ih + th@W_hh ----
        {
            const int j = tid & 255, h = tid >> 8;
            float a0 = 0.f, a1 = 0.f;
            const float* x0 = sX[2*h];
            const float* x1 = sX[2*h+1];
            for (int k = 0; k < G4; k += 4) {
                float w0 = W_ih[(k+0)*G4+j], w1 = W_ih[(k+1)*G4+j];
                float w2 = W_ih[(k+2)*G4+j], w3 = W_ih[(k+3)*G4+j];
                float4 v0 = *(const float4*)&x0[k];
                float4 v1 = *(const float4*)&x1[k];
                a0 += v0.x*w0 + v0.y*w1 + v0.z*w2 + v0.w*w3;
                a1 += v1.x*w0 + v1.y*w1 + v1.z*w2 + v1.w*w3;
            }
            const float* t0 = sTh[2*h];
            const float* t1 = sTh[2*h+1];
            for (int k = 0; k < TS; k += 4) {
                float w0 = W_hh[(k+0)*G4+j], w1 = W_hh[(k+1)*G4+j];
                float w2 = W_hh[(k+2)*G4+j], w3 = W_hh[(k+3)*G4+j];
                float4 v0 = *(const float4*)&t0[k];
                float4 v1 = *(const float4*)&t1[k];
                a0 += v0.x*w0 + v0.y*w1 + v0.z*w2 + v0.w*w3;
                a1 += v1.x*w0 + v1.y*w1 + v1.z*w2 + v1.w*w3;
            }
            sG[2*h][j] = a0; sG[2*h+1][j] = a1;
        }
        __syncthreads();

        // ---- P4: tracking LSTM pointwise + logits/nll (4 waves) ----
        if (tid < RPB*TS) {
            int r = tid >> 6, k = tid & 63;
            float gi = sG[r][k], gf = sG[r][TS+k], gg = sG[r][2*TS+k], go = sG[r][3*TS+k];
            float tcn = sigf(gf)*sTc[r][k] + sigf(gi)*tanhf(gg);
            float thn = sigf(go)*tanhf(tcn);
            sTc[r][k] = tcn; sTh[r][k] = thn;
            float p0 = thn * Wt[2*k + 0];
            float p1 = thn * Wt[2*k + 1];
            #pragma unroll
            for (int o = 32; o > 0; o >>= 1) {
                p0 += __shfl_xor(p0, o, 64);
                p1 += __shfl_xor(p1, o, 64);
            }
            if (k == 0) {
                float l0 = p0 + bt[0], l1 = p1 + bt[1];
                float m = fmaxf(l0, l1);
                float lse = m + logf(expf(l0-m) + expf(l1-m));
                sNll[r] += lse - (sTr[r] ? l1 : l0);
            }
        }
        __syncthreads();

        // ---- P5: r = s2h@WL + bL + s1h@WR + th_new@Wtr  (reduce rows only) ----
        const int anyRed = sTr[0] | sTr[1] | sTr[2] | sTr[3];
        if (anyRed) {
            const bool a0 = sTr[0], a1 = sTr[1], a2 = sTr[2], a3 = sTr[3];
            const int c0 = tid, c1 = tid + 512, c2 = tid + 1024;
            float acc[RPB][3];
            #pragma unroll
            for (int r = 0; r < RPB; ++r) {
                acc[r][0] = bL[c0];
                acc[r][1] = bL[c1];
                acc[r][2] = (c2 < R5) ? bL[c2] : 0.f;   // only OOB-guard needed
            }
            for (int k = 0; k < SZ; k += 4) {
                float wl[4][3], wr[4][3];
                #pragma unroll
                for (int kk = 0; kk < 4; ++kk) {
                    wl[kk][0] = WL[(size_t)(k+kk)*R5 + c0];
                    wl[kk][1] = WL[(size_t)(k+kk)*R5 + c1];
                    wl[kk][2] = WL[(size_t)(k+kk)*R5 + c2];   // in-allocation even if c2>=1500 (value unused)
                    wr[kk][0] = WR[(size_t)(k+kk)*R5 + c0];
                    wr[kk][1] = WR[(size_t)(k+kk)*R5 + c1];
                    wr[kk][2] = WR[(size_t)(k+kk)*R5 + c2];
                }
                #pragma unroll
                for (int r = 0; r < RPB; ++r) {
                    bool act = (r==0) ? a0 : (r==1) ? a1 : (r==2) ? a2 : a3;
                    if (act) {
                        float4 h2 = *(const float4*)&sInp[r][608 + k];
                        float4 h1 = *(const float4*)&sInp[r][304 + k];
                        #pragma unroll
                        for (int p = 0; p < 3; ++p) {
                            acc[r][p] += h2.x*wl[0][p] + h2.y*wl[1][p] + h2.z*wl[2][p] + h2.w*wl[3][p]
                                       + h1.x*wr[0][p] + h1.y*wr[1][p] + h1.z*wr[2][p] + h1.w*wr[3][p];
                        }
                    }
                }
            }
            for (int k = 0; k < TS; k += 4) {
                float wt[4][3];
                #pragma unroll
                for (int kk = 0; kk < 4; ++kk) {
                    wt[kk][0] = Wtr[(size_t)(k+kk)*R5 + c0];
                    wt[kk][1] = Wtr[(size_t)(k+kk)*R5 + c1];
                    wt[kk][2] = Wtr[(size_t)(k+kk)*R5 + c2];
                }
                #pragma unroll
                for (int r = 0; r < RPB; ++r) {
                    bool act = (r==0) ? a0 : (r==1) ? a1 : (r==2) ? a2 : a3;
                    if (act) {
                        float4 tv = *(const float4*)&sTh[r][k];
                        #pragma unroll
                        for (int p = 0; p < 3; ++p)
                            acc[r][p] += tv.x*wt[0][p] + tv.y*wt[1][p] + tv.z*wt[2][p] + tv.w*wt[3][p];
                    }
                }
            }
            #pragma unroll
            for (int r = 0; r < RPB; ++r) {
                bool act = (r==0) ? a0 : (r==1) ? a1 : (r==2) ? a2 : a3;
                if (act) {
                    sR[r][c0] = acc[r][0];
                    sR[r][c1] = acc[r][1];
                    if (c2 < R5) sR[r][c2] = acc[r][2];
                }
            }
        }
        __syncthreads();

        // ---- P6: tree-LSTM pointwise, write [rh|rc] into stack slot sp-2 ----
        if (anyRed) {
            for (int idx = tid; idx < RPB*SZ; idx += NTHR) {
                int r = idx / SZ, c = idx - r*SZ;
                if (sTr[r]) {
                    int b = b0 + r;
                    float ra  = sR[r][c],        ri = sR[r][SZ+c], rf1 = sR[r][2*SZ+c];
                    float rf2 = sR[r][3*SZ+c],   ro = sR[r][4*SZ+c];
                    int cc1 = sS1[r], cc2 = sS2[r];
                    float s1c = (cc1 >= 0) ? tokens[((size_t)b*NS + cc1)*600 + SZ + c]
                                           : stack [((size_t)b*NS + sS1sl[r])*600 + SZ + c];
                    float s2c = (cc2 >= 0) ? tokens[((size_t)b*NS + cc2)*600 + SZ + c]
                                           : stack [((size_t)b*NS + sS2sl[r])*600 + SZ + c];
                    float rc = tanhf(ra)*sigf(ri) + sigf(rf1)*s2c + sigf(rf2)*s1c;
                    float rh = sigf(ro)*tanhf(rc);
                    float* dst = stack + ((size_t)b*NS + sWsl[r])*600;
                    dst[c]      = rh;
                    dst[SZ + c] = rc;
                }
            }
        }
    } // t loop

    // ---- finalize: apply last transition, write final items + per-row nll ----
    __syncthreads();
    if (tid < RPB) {
        int r = tid;
        if (prevTr) { srcS[r][sp-2] = -1; sp -= 1; }
        else        { if (sp < NS) srcS[r][sp] = bp; sp += 1; bp += 1; }
        int fsl = min(max(sp-1,0), NS-1);
        sS1sl[r] = fsl;
        sS1[r] = (sp >= 1) ? srcS[r][fsl] : -3;
        nllrow[b0 + r] = sNll[r];
    }
    __syncthreads();
    for (int idx = tid; idx < RPB*600; idx += NTHR) {
        int r = idx / 600, i = idx - r*600;
        int b = b0 + r;
        int c = sS1[r];
        float v = 0.f;
        if (c >= 0)       v = tokens[((size_t)b*NS + c)*600 + i];
        else if (c == -1) v = stack [((size_t)b*NS + sS1sl[r])*600 + i];
        out[(size_t)b*600 + i] = v;
    }
}

__global__ void kNll(const float* __restrict__ nllrow, float* __restrict__ out)
{
    __shared__ float sb[512];
    int tid = threadIdx.x;
    sb[tid] = nllrow[tid];
    __syncthreads();
    for (int s = 256; s > 0; s >>= 1) {
        if (tid < s) sb[tid] += sb[tid + s];
        __syncthreads();
    }
    if (tid == 0) out[(size_t)B_*600] = sb[0] / (float)(TT * B_);
}

// ---------------------------------------------------------------------------
extern "C" void kernel_launch(void* const* d_in, const int* in_sizes, int n_in,
                              void* d_out, int out_size, void* d_ws, size_t ws_size,
                              hipStream_t stream)
{
    const float* tokens = (const float*)d_in[0];
    const float* Wb   = (const float*)d_in[1];
    const float* Ws1  = (const float*)d_in[2];
    const float* Ws2  = (const float*)d_in[3];
    const float* W_ih = (const float*)d_in[4];
    const float* W_hh = (const float*)d_in[5];
    const float* Wt   = (const float*)d_in[6];
    const float* bt   = (const float*)d_in[7];
    const float* WL   = (const float*)d_in[8];
    const float* WR   = (const float*)d_in[9];
    const float* Wtr  = (const float*)d_in[10];
    const float* bL   = (const float*)d_in[11];
    const int* trans  = (const int*)d_in[12];
    float* out = (float*)d_out;

    char* p = (char*)d_ws;
    float* stack  = (float*)p;  p += (size_t)B_ * NS * 600 * 4;   // 157,286,400 B
    float* nllrow = (float*)p;  p += (size_t)B_ * 4;

    kSpinn<<<NBLK, NTHR, 0, stream>>>(tokens, Wb, Ws1, Ws2, W_ih, W_hh, Wt, bt,
                                      WL, WR, Wtr, bL, trans, stack, out, nllrow);
    kNll<<<1, 512, 0, stream>>>(nllrow, out);
}